// Round 1
// baseline (1208.586 us; speedup 1.0000x reference)
//
#include <hip/hip_runtime.h>
#include <math.h>

// Problem constants
#define BB 16
#define CC 128
#define NN 16384          // 128*128 spatial tokens
#define NHEADS 8
#define HD 16             // head dim (C / NHEADS)
#define SCALE 0.08838834764831843f   // 1/sqrt(128)

// ---------------------------------------------------------------------------
// k1: per-batch Gram matrix G = x x^T (128x128) and row-sum s (128)
// grid (64 chunks, 16 batches), 256 threads. Chunk = 256 columns of n.
// Each thread owns an 8x8 register tile of G; atomicAdd reduce across chunks.
// ---------------------------------------------------------------------------
__global__ __launch_bounds__(256) void k1_gram(const float* __restrict__ x,
                                               float* __restrict__ G,
                                               float* __restrict__ sB) {
    const int chunk = blockIdx.x;       // 0..63
    const int b = blockIdx.y;           // 0..15
    const int tid = threadIdx.x;
    const int ti = tid >> 4;            // 0..15 -> rows 8*ti..8*ti+7
    const int tj = tid & 15;            // 0..15 -> cols 8*tj..8*tj+7

    __shared__ float xs[32][132];       // [t][c], padded

    float acc[8][8];
#pragma unroll
    for (int u = 0; u < 8; ++u)
#pragma unroll
        for (int w = 0; w < 8; ++w) acc[u][w] = 0.0f;

    float ssum = 0.0f;
    const float* xb = x + (size_t)b * CC * NN;
    const int n_base = chunk * 256;

    for (int t0 = 0; t0 < 256; t0 += 32) {
        // cooperative load: 32 columns x 128 channels
#pragma unroll
        for (int k = 0; k < 16; ++k) {
            int idx = tid + 256 * k;     // 0..4095
            int t = idx & 31;
            int c = idx >> 5;
            xs[t][c] = xb[(size_t)c * NN + n_base + t0 + t];
        }
        __syncthreads();

        if (tid < 128) {
#pragma unroll
            for (int t = 0; t < 32; ++t) ssum += xs[t][tid];
        }

#pragma unroll
        for (int t = 0; t < 32; ++t) {
            float4 a0 = *(const float4*)&xs[t][8 * ti];
            float4 a1 = *(const float4*)&xs[t][8 * ti + 4];
            float4 b0 = *(const float4*)&xs[t][8 * tj];
            float4 b1 = *(const float4*)&xs[t][8 * tj + 4];
            float av[8] = {a0.x, a0.y, a0.z, a0.w, a1.x, a1.y, a1.z, a1.w};
            float bv[8] = {b0.x, b0.y, b0.z, b0.w, b1.x, b1.y, b1.z, b1.w};
#pragma unroll
            for (int u = 0; u < 8; ++u)
#pragma unroll
                for (int w = 0; w < 8; ++w) acc[u][w] += av[u] * bv[w];
        }
        __syncthreads();
    }

    float* Gb = G + (size_t)b * CC * CC;
#pragma unroll
    for (int u = 0; u < 8; ++u)
#pragma unroll
        for (int w = 0; w < 8; ++w)
            atomicAdd(&Gb[(8 * ti + u) * CC + (8 * tj + w)], acc[u][w]);

    if (tid < 128) atomicAdd(&sB[b * CC + tid], ssum);
}

// ---------------------------------------------------------------------------
// k2a: per-batch per-head scores + softmax.
// scores_h = (Wq_h G Wk_h^T + (Wq_h s) bk^T + bq (Wk_h s)^T + N bq bk^T)/sqrt(C)
// grid 16 blocks (one per batch), 256 threads, heads sequential.
// ---------------------------------------------------------------------------
__global__ __launch_bounds__(256) void k2a_attn(const float* __restrict__ G,
                                                const float* __restrict__ sB,
                                                const float* __restrict__ w_qkv,
                                                const float* __restrict__ b_qkv,
                                                float* __restrict__ attn,
                                                float* __restrict__ cpre) {
    const int b = blockIdx.x;
    const int tid = threadIdx.x;
    const float* Gb = G + (size_t)b * CC * CC;
    const float* sb = sB + b * CC;

    __shared__ float Tq[HD][132];
    __shared__ float sc[HD][HD];
    __shared__ float qs[HD], ks[HD];

    for (int h = 0; h < NHEADS; ++h) {
        // stage A: Tq[dd][c2] = sum_c1 Wq[h*16+dd][c1] * G[c1][c2]
        for (int idx = tid; idx < HD * CC; idx += 256) {
            int dd = idx >> 7, c2 = idx & 127;
            const float* wq = w_qkv + (h * HD + dd) * CC;
            float sum = 0.0f;
            for (int c1 = 0; c1 < CC; ++c1) sum += wq[c1] * Gb[c1 * CC + c2];
            Tq[dd][c2] = sum;
        }
        if (tid < HD) {
            const float* wq = w_qkv + (h * HD + tid) * CC;
            float sum = 0.0f;
            for (int c = 0; c < CC; ++c) sum += wq[c] * sb[c];
            qs[tid] = sum;
        } else if (tid < 2 * HD) {
            int e = tid - HD;
            const float* wk = w_qkv + (CC + h * HD + e) * CC;
            float sum = 0.0f;
            for (int c = 0; c < CC; ++c) sum += wk[c] * sb[c];
            ks[e] = sum;
        }
        __syncthreads();

        // stage B: 256 threads = 16x16 score entries
        {
            int dd = tid >> 4, e = tid & 15;
            const float* wk = w_qkv + (CC + h * HD + e) * CC;
            float sum = 0.0f;
            for (int c2 = 0; c2 < CC; ++c2) sum += Tq[dd][c2] * wk[c2];
            float bq = b_qkv[h * HD + dd];
            float bk = b_qkv[CC + h * HD + e];
            sum += qs[dd] * bk + bq * ks[e] + (float)NN * bq * bk;
            sc[dd][e] = sum * SCALE;
        }
        __syncthreads();

        // softmax per row + cpre = attn @ b_v
        if (tid < HD) {
            int dd = tid;
            float mx = -1e30f;
#pragma unroll
            for (int e = 0; e < HD; ++e) mx = fmaxf(mx, sc[dd][e]);
            float ex[HD];
            float den = 0.0f;
#pragma unroll
            for (int e = 0; e < HD; ++e) { ex[e] = expf(sc[dd][e] - mx); den += ex[e]; }
            float inv = 1.0f / den;
            float cp = 0.0f;
#pragma unroll
            for (int e = 0; e < HD; ++e) {
                float a = ex[e] * inv;
                attn[(((size_t)b * NHEADS + h) * HD + dd) * HD + e] = a;
                cp += a * b_qkv[2 * CC + h * HD + e];
            }
            cpre[b * CC + h * HD + dd] = cp;
        }
        __syncthreads();
    }
}

// ---------------------------------------------------------------------------
// k2b: per-batch M = W_out * blockdiag(attn) * W_v   (128x128)
//      cvec = W_out * cpre + b_out
// grid 16 blocks, 256 threads.
// ---------------------------------------------------------------------------
__global__ __launch_bounds__(256) void k2b_M(const float* __restrict__ attn,
                                             const float* __restrict__ cpre,
                                             const float* __restrict__ w_qkv,
                                             const float* __restrict__ w_out,
                                             const float* __restrict__ b_out,
                                             float* __restrict__ Mw,
                                             float* __restrict__ cvec) {
    const int b = blockIdx.x;
    const int tid = threadIdx.x;
    __shared__ float P[CC][CC];   // 64 KB: P = blockdiag(attn) * W_v

    for (int idx = tid; idx < CC * CC; idx += 256) {
        int r = idx >> 7, c = idx & 127;
        int h = r >> 4, dd = r & 15;
        const float* ab = attn + (((size_t)b * NHEADS + h) * HD + dd) * HD;
        float sum = 0.0f;
#pragma unroll
        for (int e = 0; e < HD; ++e) sum += ab[e] * w_qkv[(2 * CC + h * HD + e) * CC + c];
        P[r][c] = sum;
    }
    __syncthreads();

    for (int idx = tid; idx < CC * CC; idx += 256) {
        int o = idx >> 7, c = idx & 127;
        const float* wo = w_out + o * CC;
        float sum = 0.0f;
        for (int r = 0; r < CC; ++r) sum += wo[r] * P[r][c];
        Mw[(size_t)b * CC * CC + o * CC + c] = sum;
    }
    if (tid < CC) {
        float sum = 0.0f;
        for (int r = 0; r < CC; ++r) sum += w_out[tid * CC + r] * cpre[b * CC + r];
        cvec[b * CC + tid] = sum + b_out[tid];
    }
}

// ---------------------------------------------------------------------------
// k3: y = M_b x + c_b. grid (32 n-chunks, 4 row-quarters, 16 b), 256 threads.
// Each thread: 2 columns x 32 rows. M quarter staged in LDS (16 KB).
// ---------------------------------------------------------------------------
__global__ __launch_bounds__(256) void k3_out(const float* __restrict__ x,
                                              const float* __restrict__ Mw,
                                              const float* __restrict__ cvec,
                                              float* __restrict__ y) {
    const int chunk = blockIdx.x;    // 0..31 -> 512 columns
    const int quarter = blockIdx.y;  // 0..3  -> 32 rows
    const int b = blockIdx.z;
    const int tid = threadIdx.x;

    __shared__ float Ms[32][CC];     // 16 KB
    __shared__ float cs[32];

#pragma unroll
    for (int k = 0; k < 16; ++k) {
        int idx = tid + 256 * k;     // 0..4095
        int o = idx >> 7, c = idx & 127;
        Ms[o][c] = Mw[(size_t)b * CC * CC + (quarter * 32 + o) * CC + c];
    }
    if (tid < 32) cs[tid] = cvec[b * CC + quarter * 32 + tid];
    __syncthreads();

    const float* xb = x + (size_t)b * CC * NN;
    const int na = chunk * 512 + tid;
    const int nb = na + 256;

    float acc[2][32];
#pragma unroll
    for (int o = 0; o < 32; ++o) { acc[0][o] = 0.0f; acc[1][o] = 0.0f; }

    for (int c = 0; c < CC; c += 4) {
        float xa0 = xb[(size_t)(c + 0) * NN + na];
        float xa1 = xb[(size_t)(c + 1) * NN + na];
        float xa2 = xb[(size_t)(c + 2) * NN + na];
        float xa3 = xb[(size_t)(c + 3) * NN + na];
        float xb0 = xb[(size_t)(c + 0) * NN + nb];
        float xb1 = xb[(size_t)(c + 1) * NN + nb];
        float xb2 = xb[(size_t)(c + 2) * NN + nb];
        float xb3 = xb[(size_t)(c + 3) * NN + nb];
#pragma unroll
        for (int o = 0; o < 32; ++o) {
            float4 m = *(const float4*)&Ms[o][c];
            acc[0][o] += m.x * xa0 + m.y * xa1 + m.z * xa2 + m.w * xa3;
            acc[1][o] += m.x * xb0 + m.y * xb1 + m.z * xb2 + m.w * xb3;
        }
    }

    float* yb = y + (size_t)b * CC * NN;
#pragma unroll
    for (int o = 0; o < 32; ++o) {
        int row = quarter * 32 + o;
        yb[(size_t)row * NN + na] = acc[0][o] + cs[o];
        yb[(size_t)row * NN + nb] = acc[1][o] + cs[o];
    }
}

// ---------------------------------------------------------------------------
extern "C" void kernel_launch(void* const* d_in, const int* in_sizes, int n_in,
                              void* d_out, int out_size, void* d_ws, size_t ws_size,
                              hipStream_t stream) {
    const float* x     = (const float*)d_in[0];
    const float* w_qkv = (const float*)d_in[1];
    const float* b_qkv = (const float*)d_in[2];
    const float* w_out = (const float*)d_in[3];
    const float* b_out = (const float*)d_in[4];
    float* y = (float*)d_out;

    // workspace layout (floats): G | sB | attn | cpre | M | cvec  (~2.2 MB)
    float* G    = (float*)d_ws;
    float* sB   = G + (size_t)BB * CC * CC;
    float* attn = sB + BB * CC;
    float* cpre = attn + BB * NHEADS * HD * HD;
    float* Mw   = cpre + BB * CC;
    float* cvec = Mw + (size_t)BB * CC * CC;

    // zero G and sB (contiguous at start of ws); attn/cpre/M/cvec fully written
    hipMemsetAsync(d_ws, 0, (size_t)(BB * CC * CC + BB * CC) * sizeof(float), stream);

    k1_gram<<<dim3(64, BB), 256, 0, stream>>>(x, G, sB);
    k2a_attn<<<BB, 256, 0, stream>>>(G, sB, w_qkv, b_qkv, attn, cpre);
    k2b_M<<<BB, 256, 0, stream>>>(attn, cpre, w_qkv, w_out, b_out, Mw, cvec);
    k3_out<<<dim3(32, 4, BB), 256, 0, stream>>>(x, Mw, cvec, y);
}

// Round 2
// 973.027 us; speedup vs baseline: 1.2421x; 1.2421x over previous
//
#include <hip/hip_runtime.h>
#include <math.h>

// Problem constants
#define BB 16
#define CC 128
#define NN 16384          // 128*128 spatial tokens
#define NHEADS 8
#define HD 16             // head dim
#define SCALE 0.08838834764831843f   // 1/sqrt(128)

// ---------------------------------------------------------------------------
// k1: per-batch partial Gram. grid (CH, 16), 256 threads.
// Block owns NCB = NN/CH columns; 8x8 register tile per thread.
// Writes partial to pG[block] in permuted layout [slot(64)][tid(256)] --
// fully coalesced, NO atomics.
// ---------------------------------------------------------------------------
__global__ __launch_bounds__(256) void k1_gram(const float* __restrict__ x,
                                               float* __restrict__ pG,
                                               float* __restrict__ pS,
                                               int CH) {
    const int chunk = blockIdx.x;
    const int b = blockIdx.y;
    const int tid = threadIdx.x;
    const int ti = tid >> 4;
    const int tj = tid & 15;
    const int NCB = NN / CH;

    __shared__ float xs[32][132];

    float acc[8][8];
#pragma unroll
    for (int u = 0; u < 8; ++u)
#pragma unroll
        for (int w = 0; w < 8; ++w) acc[u][w] = 0.0f;

    float ssum = 0.0f;
    const float* xb = x + (size_t)b * CC * NN;
    const int n0 = chunk * NCB;

    for (int t0 = 0; t0 < NCB; t0 += 32) {
#pragma unroll
        for (int k = 0; k < 16; ++k) {
            int idx = tid + 256 * k;
            int t = idx & 31;
            int c = idx >> 5;
            xs[t][c] = xb[(size_t)c * NN + n0 + t0 + t];
        }
        __syncthreads();

        if (tid < 128) {
#pragma unroll
            for (int t = 0; t < 32; ++t) ssum += xs[t][tid];
        }

#pragma unroll
        for (int t = 0; t < 32; ++t) {
            float4 a0 = *(const float4*)&xs[t][8 * ti];
            float4 a1 = *(const float4*)&xs[t][8 * ti + 4];
            float4 b0 = *(const float4*)&xs[t][8 * tj];
            float4 b1 = *(const float4*)&xs[t][8 * tj + 4];
            float av[8] = {a0.x, a0.y, a0.z, a0.w, a1.x, a1.y, a1.z, a1.w};
            float bv[8] = {b0.x, b0.y, b0.z, b0.w, b1.x, b1.y, b1.z, b1.w};
#pragma unroll
            for (int u = 0; u < 8; ++u)
#pragma unroll
                for (int w = 0; w < 8; ++w) acc[u][w] += av[u] * bv[w];
        }
        __syncthreads();
    }

    // permuted coalesced store: slot s = u*8+w, lane = tid
    float* out = pG + ((size_t)(b * CH + chunk) << 14);
#pragma unroll
    for (int u = 0; u < 8; ++u)
#pragma unroll
        for (int w = 0; w < 8; ++w)
            out[(u * 8 + w) * 256 + tid] = acc[u][w];

    if (tid < 128) pS[(b * CH + chunk) * 128 + tid] = ssum;
}

// ---------------------------------------------------------------------------
// k1r: reduce partials -> G (normal layout) and sB. grid 16, 256 threads.
// ---------------------------------------------------------------------------
__global__ __launch_bounds__(256) void k1_reduce(const float* __restrict__ pG,
                                                 const float* __restrict__ pS,
                                                 float* __restrict__ G,
                                                 float* __restrict__ sB,
                                                 int CH) {
    const int b = blockIdx.x;
    const int tid = threadIdx.x;
    const int row_base = 8 * (tid >> 4);
    const int col_base = 8 * (tid & 15);
    for (int s = 0; s < 64; ++s) {
        float sum = 0.0f;
        for (int ch = 0; ch < CH; ++ch)
            sum += pG[((size_t)(b * CH + ch) << 14) + s * 256 + tid];
        int u = s >> 3, w = s & 7;
        G[((size_t)b << 14) + (row_base + u) * CC + (col_base + w)] = sum;
    }
    if (tid < 128) {
        float sum = 0.0f;
        for (int ch = 0; ch < CH; ++ch) sum += pS[(b * CH + ch) * 128 + tid];
        sB[b * CC + tid] = sum;
    }
}

// ---------------------------------------------------------------------------
// k2a: per (b,h) scores + softmax. grid (8 h, 16 b), 256 threads.
// scores = (Wq G Wk^T + (Wq s) bk^T + bq (Wk s)^T + N bq bk^T) * SCALE
// ---------------------------------------------------------------------------
__global__ __launch_bounds__(256) void k2a_attn(const float* __restrict__ G,
                                                const float* __restrict__ sB,
                                                const float* __restrict__ w_qkv,
                                                const float* __restrict__ b_qkv,
                                                float* __restrict__ attn,
                                                float* __restrict__ cpre) {
    const int h = blockIdx.x;
    const int b = blockIdx.y;
    const int tid = threadIdx.x;

    __shared__ float wq_s[HD][132], wk_s[HD][132], Tq[HD][132];
    __shared__ float qs[HD], ks[HD], bqv[HD], bkv[HD], bvv[HD];
    __shared__ float sc[HD][HD + 1];

    for (int idx = tid; idx < HD * CC; idx += 256) {
        int r = idx >> 7, c = idx & 127;
        wq_s[r][c] = w_qkv[(h * HD + r) * CC + c];
        wk_s[r][c] = w_qkv[(CC + h * HD + r) * CC + c];
    }
    if (tid < HD) {
        bqv[tid] = b_qkv[h * HD + tid];
        bkv[tid] = b_qkv[CC + h * HD + tid];
        bvv[tid] = b_qkv[2 * CC + h * HD + tid];
    }
    __syncthreads();

    // qs/ks on threads 0..31
    if (tid < 32) {
        int i = tid & 15;
        bool isK = tid >= 16;
        float sum = 0.0f;
        for (int c = 0; c < CC; ++c)
            sum += (isK ? wk_s[i][c] : wq_s[i][c]) * sB[b * CC + c];
        if (isK) ks[i] = sum; else qs[i] = sum;
    }

    // Tq[dd][c2] = sum_c1 Wq[dd][c1] G[c1][c2]; thread owns c2, 8 dd values
    {
        const int c2 = tid & 127;
        const int dh = tid >> 7;
        float t[8];
#pragma unroll
        for (int j = 0; j < 8; ++j) t[j] = 0.0f;
        const float* Gb = G + ((size_t)b << 14);
        for (int c1 = 0; c1 < CC; ++c1) {
            float g = Gb[c1 * CC + c2];
#pragma unroll
            for (int j = 0; j < 8; ++j) t[j] += wq_s[dh * 8 + j][c1] * g;
        }
        __syncthreads();   // qs/ks done; safe to publish Tq next
#pragma unroll
        for (int j = 0; j < 8; ++j) Tq[dh * 8 + j][c2] = t[j];
    }
    __syncthreads();

    // scores: thread = (dd, e)
    {
        const int dd = tid >> 4, e = tid & 15;
        float sum = 0.0f;
        for (int c2 = 0; c2 < CC; ++c2) sum += Tq[dd][c2] * wk_s[e][c2];
        sum += qs[dd] * bkv[e] + bqv[dd] * ks[e] + (float)NN * bqv[dd] * bkv[e];
        sc[dd][e] = sum * SCALE;
    }
    __syncthreads();

    if (tid < HD) {
        const int dd = tid;
        float mx = -1e30f;
#pragma unroll
        for (int e = 0; e < HD; ++e) mx = fmaxf(mx, sc[dd][e]);
        float ex[HD];
        float den = 0.0f;
#pragma unroll
        for (int e = 0; e < HD; ++e) { ex[e] = __expf(sc[dd][e] - mx); den += ex[e]; }
        float inv = 1.0f / den;
        float cp = 0.0f;
#pragma unroll
        for (int e = 0; e < HD; ++e) {
            float a = ex[e] * inv;
            attn[((size_t)b * NHEADS + h) * HD * HD + dd * HD + e] = a;
            cp += a * bvv[e];
        }
        cpre[b * CC + h * HD + dd] = cp;
    }
}

// ---------------------------------------------------------------------------
// k2b: Mt[b][c][o] = (W_out * blockdiag(attn) * W_v)^T, cvec = W_out cpre + b_out
// grid (4 ogroups, 16 b), 256 threads. Per-head P_h (16x128) in LDS.
// ---------------------------------------------------------------------------
__global__ __launch_bounds__(256) void k2b_M(const float* __restrict__ attn,
                                             const float* __restrict__ cpre,
                                             const float* __restrict__ w_qkv,
                                             const float* __restrict__ w_out,
                                             const float* __restrict__ b_out,
                                             float* __restrict__ Mt,
                                             float* __restrict__ cvec) {
    const int og = blockIdx.x;   // rows og*32..+31 of M
    const int b = blockIdx.y;
    const int tid = threadIdx.x;

    __shared__ float Ph[HD][132];
    __shared__ float wo_s[32][129];
    __shared__ float attn_s[CC][HD];
    __shared__ float cpre_s[CC];

    for (int idx = tid; idx < CC * HD; idx += 256)
        attn_s[idx >> 4][idx & 15] = attn[(size_t)b * CC * HD + idx];
    for (int idx = tid; idx < 32 * CC; idx += 256)
        wo_s[idx >> 7][idx & 127] = w_out[(og * 32 + (idx >> 7)) * CC + (idx & 127)];
    if (tid < CC) cpre_s[tid] = cpre[b * CC + tid];
    __syncthreads();

    const int c = tid & 127;
    const int oh = tid >> 7;     // 0/1 -> 16-row half
    float m[16];
#pragma unroll
    for (int j = 0; j < 16; ++j) m[j] = 0.0f;

    for (int hh = 0; hh < NHEADS; ++hh) {
        for (int idx = tid; idx < HD * CC; idx += 256) {
            int dd = idx >> 7, cc = idx & 127;
            float s = 0.0f;
#pragma unroll
            for (int e = 0; e < HD; ++e)
                s += attn_s[hh * HD + dd][e] * w_qkv[(2 * CC + hh * HD + e) * CC + cc];
            Ph[dd][cc] = s;
        }
        __syncthreads();
#pragma unroll
        for (int dd = 0; dd < HD; ++dd) {
            float p = Ph[dd][c];
#pragma unroll
            for (int j = 0; j < 16; ++j)
                m[j] += wo_s[oh * 16 + j][hh * HD + dd] * p;
        }
        __syncthreads();
    }

    float* mt = Mt + ((size_t)b << 14) + c * CC + og * 32 + oh * 16;
#pragma unroll
    for (int j = 0; j < 16; ++j) mt[j] = m[j];

    if (tid < 32) {
        float s = 0.0f;
        for (int r = 0; r < CC; ++r) s += wo_s[tid][r] * cpre_s[r];
        cvec[b * CC + og * 32 + tid] = s + b_out[og * 32 + tid];
    }
}

// ---------------------------------------------------------------------------
// k3: y = M x + c. grid (64 colchunks, 2 rowhalves, 16 b), 256 threads.
// Mt slice (transposed, stride 68 => 16B-aligned rows) in LDS; 8x8 per thread.
// ---------------------------------------------------------------------------
__global__ __launch_bounds__(256) void k3_out(const float* __restrict__ x,
                                              const float* __restrict__ Mt,
                                              const float* __restrict__ cvec,
                                              float* __restrict__ y) {
    const int chunk = blockIdx.x;   // 256 columns
    const int rh = blockIdx.y;      // 64-row half
    const int b = blockIdx.z;
    const int tid = threadIdx.x;

    __shared__ float Mts[CC][68];   // [c][o'], o' = row - rh*64
    __shared__ float cs[64];

    for (int idx = tid; idx < CC * 64; idx += 256) {
        int o = idx & 63, c = idx >> 6;
        Mts[c][o] = Mt[((size_t)b << 14) + c * CC + rh * 64 + o];
    }
    if (tid < 64) cs[tid] = cvec[b * CC + rh * 64 + tid];
    __syncthreads();

    const int rg = tid >> 5;                 // 8 row-groups of 8
    const float* xb = x + (size_t)b * CC * NN + chunk * 256 + (tid & 31) * 8;

    float acc[8][8];
#pragma unroll
    for (int u = 0; u < 8; ++u)
#pragma unroll
        for (int w = 0; w < 8; ++w) acc[u][w] = 0.0f;

    for (int c = 0; c < CC; ++c) {
        float4 xa = *(const float4*)&xb[(size_t)c * NN];
        float4 xc4 = *(const float4*)&xb[(size_t)c * NN + 4];
        float4 m0 = *(const float4*)&Mts[c][rg * 8];
        float4 m1 = *(const float4*)&Mts[c][rg * 8 + 4];
        float mr[8] = {m0.x, m0.y, m0.z, m0.w, m1.x, m1.y, m1.z, m1.w};
        float xv[8] = {xa.x, xa.y, xa.z, xa.w, xc4.x, xc4.y, xc4.z, xc4.w};
#pragma unroll
        for (int u = 0; u < 8; ++u)
#pragma unroll
            for (int w = 0; w < 8; ++w) acc[u][w] += mr[u] * xv[w];
    }

    float* yb = y + (size_t)b * CC * NN + (size_t)(rh * 64 + rg * 8) * NN + chunk * 256 + (tid & 31) * 8;
#pragma unroll
    for (int u = 0; u < 8; ++u) {
        float cadd = cs[rg * 8 + u];
        float4 o0 = {acc[u][0] + cadd, acc[u][1] + cadd, acc[u][2] + cadd, acc[u][3] + cadd};
        float4 o1 = {acc[u][4] + cadd, acc[u][5] + cadd, acc[u][6] + cadd, acc[u][7] + cadd};
        *(float4*)&yb[(size_t)u * NN] = o0;
        *(float4*)&yb[(size_t)u * NN + 4] = o1;
    }
}

// ---------------------------------------------------------------------------
extern "C" void kernel_launch(void* const* d_in, const int* in_sizes, int n_in,
                              void* d_out, int out_size, void* d_ws, size_t ws_size,
                              hipStream_t stream) {
    const float* x     = (const float*)d_in[0];
    const float* w_qkv = (const float*)d_in[1];
    const float* b_qkv = (const float*)d_in[2];
    const float* w_out = (const float*)d_in[3];
    const float* b_out = (const float*)d_in[4];
    float* y = (float*)d_out;

    // fixed-size tail of workspace (floats)
    const size_t szG = (size_t)BB * CC * CC;         // 262144
    const size_t szS = (size_t)BB * CC;              // 2048
    const size_t szAttn = (size_t)BB * NHEADS * HD * HD;
    const size_t tail = szG + szS + szAttn + szS + szG + szS;

    // choose partial-chunk count CH by available workspace
    int CH = 32;
    while (CH > 1 &&
           ((size_t)CH * BB * CC * CC + (size_t)CH * BB * CC + tail) * sizeof(float) > ws_size)
        CH >>= 1;

    float* pG   = (float*)d_ws;
    float* pS   = pG + (size_t)CH * BB * CC * CC;
    float* G    = pS + (size_t)CH * BB * CC;
    float* sB   = G + szG;
    float* attn = sB + szS;
    float* cpre = attn + szAttn;
    float* Mt   = cpre + szS;
    float* cvec = Mt + szG;

    k1_gram<<<dim3(CH, BB), 256, 0, stream>>>(x, pG, pS, CH);
    k1_reduce<<<BB, 256, 0, stream>>>(pG, pS, G, sB, CH);
    k2a_attn<<<dim3(NHEADS, BB), 256, 0, stream>>>(G, sB, w_qkv, b_qkv, attn, cpre);
    k2b_M<<<dim3(4, BB), 256, 0, stream>>>(attn, cpre, w_qkv, w_out, b_out, Mt, cvec);
    k3_out<<<dim3(64, 2, BB), 256, 0, stream>>>(x, Mt, cvec, y);
}

// Round 3
// 472.156 us; speedup vs baseline: 2.5597x; 2.0608x over previous
//
#include <hip/hip_runtime.h>
#include <math.h>

// Problem constants
#define BB 16
#define CC 128
#define NN 16384          // 128*128 spatial tokens
#define NHEADS 8
#define HD 16             // head dim
#define SCALE 0.08838834764831843f   // 1/sqrt(128)

// ---------------------------------------------------------------------------
// k1: per-batch partial Gram. grid (CH, 2 rowhalves, 16 b), 256 threads.
// Block owns NCB = NN/CH columns x 64 Gram rows; 4x8 register tile per thread
// (rows rh*64 + 4*ti..+3; cols {4*tj..+3} u {64+4*tj..+3} -- 2-way LDS banks).
// Writes partial to pG in permuted layout [slot(32)][tid(256)], coalesced.
// ---------------------------------------------------------------------------
__global__ __launch_bounds__(256) void k1_gram(const float* __restrict__ x,
                                               float* __restrict__ pG,
                                               float* __restrict__ pS,
                                               int CH) {
    const int chunk = blockIdx.x;
    const int rh = blockIdx.y;          // row half: rows rh*64..rh*64+63
    const int b = blockIdx.z;
    const int tid = threadIdx.x;
    const int ti = tid >> 4;            // 0..15 -> rows rh*64 + 4*ti..+3
    const int tj = tid & 15;            // 0..15 -> cols 4*tj & 64+4*tj
    const int NCB = NN / CH;

    __shared__ float xs[32][132];

    float acc[4][8];
#pragma unroll
    for (int u = 0; u < 4; ++u)
#pragma unroll
        for (int w = 0; w < 8; ++w) acc[u][w] = 0.0f;

    float ssum = 0.0f;
    const float* xb = x + (size_t)b * CC * NN;
    const int n0 = chunk * NCB;

    for (int t0 = 0; t0 < NCB; t0 += 32) {
#pragma unroll
        for (int k = 0; k < 16; ++k) {
            int idx = tid + 256 * k;
            int t = idx & 31;
            int c = idx >> 5;
            xs[t][c] = xb[(size_t)c * NN + n0 + t0 + t];
        }
        __syncthreads();

        if (rh == 0 && tid < 128) {
#pragma unroll
            for (int t = 0; t < 32; ++t) ssum += xs[t][tid];
        }

#pragma unroll
        for (int t = 0; t < 32; ++t) {
            float4 a0 = *(const float4*)&xs[t][rh * 64 + 4 * ti];
            float4 b0 = *(const float4*)&xs[t][4 * tj];
            float4 b1 = *(const float4*)&xs[t][64 + 4 * tj];
            float av[4] = {a0.x, a0.y, a0.z, a0.w};
            float bv[8] = {b0.x, b0.y, b0.z, b0.w, b1.x, b1.y, b1.z, b1.w};
#pragma unroll
            for (int u = 0; u < 4; ++u)
#pragma unroll
                for (int w = 0; w < 8; ++w) acc[u][w] += av[u] * bv[w];
        }
        __syncthreads();
    }

    // permuted coalesced store: slot s = u*8+w
    float* out = pG + ((size_t)((b * CH + chunk) * 2 + rh) << 13);
#pragma unroll
    for (int u = 0; u < 4; ++u)
#pragma unroll
        for (int w = 0; w < 8; ++w)
            out[(u * 8 + w) * 256 + tid] = acc[u][w];

    if (rh == 0 && tid < 128) pS[(b * CH + chunk) * 128 + tid] = ssum;
}

// ---------------------------------------------------------------------------
// k1r: reduce partials -> G, sB. grid (64, 16): block = (rh*32+s, b).
// 256 threads, each sums CH coalesced values.
// ---------------------------------------------------------------------------
__global__ __launch_bounds__(256) void k1_reduce(const float* __restrict__ pG,
                                                 const float* __restrict__ pS,
                                                 float* __restrict__ G,
                                                 float* __restrict__ sB,
                                                 int CH) {
    const int sg = blockIdx.x;   // 0..63
    const int b = blockIdx.y;
    const int rh = sg >> 5, s = sg & 31;
    const int tid = threadIdx.x;

    float sum = 0.0f;
    for (int ch = 0; ch < CH; ++ch)
        sum += pG[((size_t)((b * CH + ch) * 2 + rh) << 13) + s * 256 + tid];

    const int u = s >> 3, w = s & 7;
    const int ti = tid >> 4, tj = tid & 15;
    const int row = rh * 64 + 4 * ti + u;
    const int col = (w < 4) ? (4 * tj + w) : (64 + 4 * tj + (w - 4));
    G[((size_t)b << 14) + row * CC + col] = sum;

    if (sg == 0 && tid < 128) {
        float s2 = 0.0f;
        for (int ch = 0; ch < CH; ++ch) s2 += pS[(b * CH + ch) * 128 + tid];
        sB[b * CC + tid] = s2;
    }
}

// ---------------------------------------------------------------------------
// k2a: per (b,h) scores + softmax. grid (8 h, 16 b), 256 threads.
// scores = (Wq G Wk^T + (Wq s) bk^T + bq (Wk s)^T + N bq bk^T) * SCALE
// ---------------------------------------------------------------------------
__global__ __launch_bounds__(256) void k2a_attn(const float* __restrict__ G,
                                                const float* __restrict__ sB,
                                                const float* __restrict__ w_qkv,
                                                const float* __restrict__ b_qkv,
                                                float* __restrict__ attn,
                                                float* __restrict__ cpre) {
    const int h = blockIdx.x;
    const int b = blockIdx.y;
    const int tid = threadIdx.x;

    __shared__ float wq_s[HD][132], wk_s[HD][132], Tq[HD][132];
    __shared__ float qs[HD], ks[HD], bqv[HD], bkv[HD], bvv[HD];
    __shared__ float sc[HD][HD + 1];

    for (int idx = tid; idx < HD * CC; idx += 256) {
        int r = idx >> 7, c = idx & 127;
        wq_s[r][c] = w_qkv[(h * HD + r) * CC + c];
        wk_s[r][c] = w_qkv[(CC + h * HD + r) * CC + c];
    }
    if (tid < HD) {
        bqv[tid] = b_qkv[h * HD + tid];
        bkv[tid] = b_qkv[CC + h * HD + tid];
        bvv[tid] = b_qkv[2 * CC + h * HD + tid];
    }
    __syncthreads();

    if (tid < 32) {
        int i = tid & 15;
        bool isK = tid >= 16;
        float sum = 0.0f;
        for (int c = 0; c < CC; ++c)
            sum += (isK ? wk_s[i][c] : wq_s[i][c]) * sB[b * CC + c];
        if (isK) ks[i] = sum; else qs[i] = sum;
    }

    {
        const int c2 = tid & 127;
        const int dh = tid >> 7;
        float t[8];
#pragma unroll
        for (int j = 0; j < 8; ++j) t[j] = 0.0f;
        const float* Gb = G + ((size_t)b << 14);
        for (int c1 = 0; c1 < CC; ++c1) {
            float g = Gb[c1 * CC + c2];
#pragma unroll
            for (int j = 0; j < 8; ++j) t[j] += wq_s[dh * 8 + j][c1] * g;
        }
        __syncthreads();
#pragma unroll
        for (int j = 0; j < 8; ++j) Tq[dh * 8 + j][c2] = t[j];
    }
    __syncthreads();

    {
        const int dd = tid >> 4, e = tid & 15;
        float sum = 0.0f;
        for (int c2 = 0; c2 < CC; ++c2) sum += Tq[dd][c2] * wk_s[e][c2];
        sum += qs[dd] * bkv[e] + bqv[dd] * ks[e] + (float)NN * bqv[dd] * bkv[e];
        sc[dd][e] = sum * SCALE;
    }
    __syncthreads();

    if (tid < HD) {
        const int dd = tid;
        float mx = -1e30f;
#pragma unroll
        for (int e = 0; e < HD; ++e) mx = fmaxf(mx, sc[dd][e]);
        float ex[HD];
        float den = 0.0f;
#pragma unroll
        for (int e = 0; e < HD; ++e) { ex[e] = __expf(sc[dd][e] - mx); den += ex[e]; }
        float inv = 1.0f / den;
        float cp = 0.0f;
#pragma unroll
        for (int e = 0; e < HD; ++e) {
            float a = ex[e] * inv;
            attn[((size_t)b * NHEADS + h) * HD * HD + dd * HD + e] = a;
            cp += a * bvv[e];
        }
        cpre[b * CC + h * HD + dd] = cp;
    }
}

// ---------------------------------------------------------------------------
// k2b: Mt[b][c][o] = (W_out * blockdiag(attn) * W_v)^T, cvec = W_out cpre + b_out
// grid (4 ogroups, 16 b), 256 threads.
// ---------------------------------------------------------------------------
__global__ __launch_bounds__(256) void k2b_M(const float* __restrict__ attn,
                                             const float* __restrict__ cpre,
                                             const float* __restrict__ w_qkv,
                                             const float* __restrict__ w_out,
                                             const float* __restrict__ b_out,
                                             float* __restrict__ Mt,
                                             float* __restrict__ cvec) {
    const int og = blockIdx.x;
    const int b = blockIdx.y;
    const int tid = threadIdx.x;

    __shared__ float Ph[HD][132];
    __shared__ float wo_s[32][129];
    __shared__ float attn_s[CC][HD];
    __shared__ float cpre_s[CC];

    for (int idx = tid; idx < CC * HD; idx += 256)
        attn_s[idx >> 4][idx & 15] = attn[(size_t)b * CC * HD + idx];
    for (int idx = tid; idx < 32 * CC; idx += 256)
        wo_s[idx >> 7][idx & 127] = w_out[(og * 32 + (idx >> 7)) * CC + (idx & 127)];
    if (tid < CC) cpre_s[tid] = cpre[b * CC + tid];
    __syncthreads();

    const int c = tid & 127;
    const int oh = tid >> 7;
    float m[16];
#pragma unroll
    for (int j = 0; j < 16; ++j) m[j] = 0.0f;

    for (int hh = 0; hh < NHEADS; ++hh) {
        for (int idx = tid; idx < HD * CC; idx += 256) {
            int dd = idx >> 7, cc = idx & 127;
            float s = 0.0f;
#pragma unroll
            for (int e = 0; e < HD; ++e)
                s += attn_s[hh * HD + dd][e] * w_qkv[(2 * CC + hh * HD + e) * CC + cc];
            Ph[dd][cc] = s;
        }
        __syncthreads();
#pragma unroll
        for (int dd = 0; dd < HD; ++dd) {
            float p = Ph[dd][c];
#pragma unroll
            for (int j = 0; j < 16; ++j)
                m[j] += wo_s[oh * 16 + j][hh * HD + dd] * p;
        }
        __syncthreads();
    }

    float* mt = Mt + ((size_t)b << 14) + c * CC + og * 32 + oh * 16;
#pragma unroll
    for (int j = 0; j < 16; ++j) mt[j] = m[j];

    if (tid < 32) {
        float s = 0.0f;
        for (int r = 0; r < CC; ++r) s += wo_s[tid][r] * cpre_s[r];
        cvec[b * CC + og * 32 + tid] = s + b_out[og * 32 + tid];
    }
}

// ---------------------------------------------------------------------------
// k3: y = M x + c. grid (64 colchunks, 2 rowhalves, 16 b), 256 threads.
// ---------------------------------------------------------------------------
__global__ __launch_bounds__(256) void k3_out(const float* __restrict__ x,
                                              const float* __restrict__ Mt,
                                              const float* __restrict__ cvec,
                                              float* __restrict__ y) {
    const int chunk = blockIdx.x;
    const int rh = blockIdx.y;
    const int b = blockIdx.z;
    const int tid = threadIdx.x;

    __shared__ float Mts[CC][68];
    __shared__ float cs[64];

    for (int idx = tid; idx < CC * 64; idx += 256) {
        int o = idx & 63, c = idx >> 6;
        Mts[c][o] = Mt[((size_t)b << 14) + c * CC + rh * 64 + o];
    }
    if (tid < 64) cs[tid] = cvec[b * CC + rh * 64 + tid];
    __syncthreads();

    const int rg = tid >> 5;
    const float* xb = x + (size_t)b * CC * NN + chunk * 256 + (tid & 31) * 8;

    float acc[8][8];
#pragma unroll
    for (int u = 0; u < 8; ++u)
#pragma unroll
        for (int w = 0; w < 8; ++w) acc[u][w] = 0.0f;

    for (int c = 0; c < CC; ++c) {
        float4 xa = *(const float4*)&xb[(size_t)c * NN];
        float4 xc4 = *(const float4*)&xb[(size_t)c * NN + 4];
        float4 m0 = *(const float4*)&Mts[c][rg * 8];
        float4 m1 = *(const float4*)&Mts[c][rg * 8 + 4];
        float mr[8] = {m0.x, m0.y, m0.z, m0.w, m1.x, m1.y, m1.z, m1.w};
        float xv[8] = {xa.x, xa.y, xa.z, xa.w, xc4.x, xc4.y, xc4.z, xc4.w};
#pragma unroll
        for (int u = 0; u < 8; ++u)
#pragma unroll
            for (int w = 0; w < 8; ++w) acc[u][w] += mr[u] * xv[w];
    }

    float* yb = y + (size_t)b * CC * NN + (size_t)(rh * 64 + rg * 8) * NN + chunk * 256 + (tid & 31) * 8;
#pragma unroll
    for (int u = 0; u < 8; ++u) {
        float cadd = cs[rg * 8 + u];
        float4 o0 = {acc[u][0] + cadd, acc[u][1] + cadd, acc[u][2] + cadd, acc[u][3] + cadd};
        float4 o1 = {acc[u][4] + cadd, acc[u][5] + cadd, acc[u][6] + cadd, acc[u][7] + cadd};
        *(float4*)&yb[(size_t)u * NN] = o0;
        *(float4*)&yb[(size_t)u * NN + 4] = o1;
    }
}

// ---------------------------------------------------------------------------
extern "C" void kernel_launch(void* const* d_in, const int* in_sizes, int n_in,
                              void* d_out, int out_size, void* d_ws, size_t ws_size,
                              hipStream_t stream) {
    const float* x     = (const float*)d_in[0];
    const float* w_qkv = (const float*)d_in[1];
    const float* b_qkv = (const float*)d_in[2];
    const float* w_out = (const float*)d_in[3];
    const float* b_out = (const float*)d_in[4];
    float* y = (float*)d_out;

    const size_t szG = (size_t)BB * CC * CC;
    const size_t szS = (size_t)BB * CC;
    const size_t szAttn = (size_t)BB * NHEADS * HD * HD;
    const size_t tail = szG + szS + szAttn + szS + szG + szS;

    int CH = 32;
    while (CH > 1 &&
           ((size_t)CH * BB * CC * CC + (size_t)CH * BB * CC + tail) * sizeof(float) > ws_size)
        CH >>= 1;

    float* pG   = (float*)d_ws;
    float* pS   = pG + (size_t)CH * BB * CC * CC;   // CH*16*2*8192 == CH*BB*CC*CC
    float* G    = pS + (size_t)CH * BB * CC;
    float* sB   = G + szG;
    float* attn = sB + szS;
    float* cpre = attn + szAttn;
    float* Mt   = cpre + szS;
    float* cvec = Mt + szG;

    k1_gram<<<dim3(CH, 2, BB), 256, 0, stream>>>(x, pG, pS, CH);
    k1_reduce<<<dim3(64, BB), 256, 0, stream>>>(pG, pS, G, sB, CH);
    k2a_attn<<<dim3(NHEADS, BB), 256, 0, stream>>>(G, sB, w_qkv, b_qkv, attn, cpre);
    k2b_M<<<dim3(4, BB), 256, 0, stream>>>(attn, cpre, w_qkv, w_out, b_out, Mt, cvec);
    k3_out<<<dim3(64, 2, BB), 256, 0, stream>>>(x, Mt, cvec, y);
}